// Round 6
// baseline (284.152 us; speedup 1.0000x reference)
//
#include <hip/hip_runtime.h>
#include <hip/hip_bf16.h>

#define DD 128
#define N_SRC 200000
#define N_MID 50000
#define N_DST 10000
#define E1 800000
#define E2 160000
#define CAP 48        // bucket capacity; deg ~ Poisson(16), P(deg>48) ~ 1e-11
#define CSTR 16       // counter stride in ints (64B), store-free counter lines

typedef unsigned short u16;
typedef unsigned int u32;
typedef __attribute__((ext_vector_type(8))) short s16x8;   // 8 bf16 (4 VGPRs)
typedef __attribute__((ext_vector_type(4))) float f32x4;
typedef __attribute__((ext_vector_type(4))) int i32x4;
typedef __attribute__((ext_vector_type(4))) float fv4;

// ---------------- bf16 helpers ----------------

__device__ __forceinline__ float bf_lo(u32 u) {
    union { u32 u; float f; } v; v.u = u << 16; return v.f;
}
__device__ __forceinline__ float bf_hi(u32 u) {
    union { u32 u; float f; } v; v.u = u & 0xffff0000u; return v.f;
}
__device__ __forceinline__ u32 f2bf_bits(float f) {
    union { float f; u32 u; } v; v.f = f;
    return (v.u + 0x7fffu + ((v.u >> 16) & 1u)) >> 16;   // RTNE
}
__device__ __forceinline__ u32 pack2bf(float lo, float hi) {
    return f2bf_bits(lo) | (f2bf_bits(hi) << 16);
}

// ---------------- fused prep + fill kernel ----------------
// Fill-path change vs the verified 70us round-5 kernel: BUFFERED CLAIMS.
// Round-5 post-mortem: one atomic retired per wave per ~900cy == exactly one
// outstanding atomic per wave (store inside the divergent claim body forces a
// vmcnt drain per claim). Here all 8 claims issue their atomicAdd back-to-back
// into a register array (no dependent use), THEN a second loop does the
// dependent stores -> up to 8 outstanding atomics per wave.

#define FILL1_SLICE  4000
#define FILL1_BLOCKS 1600          // 200 slices x 8 shards
#define FILL2_SLICE  4000
#define FILL2_BLOCKS 320           // 40 slices x 8 shards
#define FILL_BLOCKS  (FILL1_BLOCKS + FILL2_BLOCKS)   // 1920

#define NCONV8 (N_SRC * DD / 8)    // 400000
#define WTF_T 8192
#define PREP_T (NCONV8 + WTF_T)
#define PREP_BLOCKS ((PREP_T + 255) / 256)           // 1595
#define PF_BLOCKS (FILL_BLOCKS + PREP_BLOCKS)

__global__ __launch_bounds__(256, 8) void prep_fill(
    const float* __restrict__ x, u16* __restrict__ xb,
    const float* __restrict__ Wl1, const float* __restrict__ Wr1,
    u16* __restrict__ WTf1,
    const float* __restrict__ Wl2, const float* __restrict__ Wr2,
    u16* __restrict__ WTf2,
    const int* __restrict__ row1, const int* __restrict__ col1,
    const int* __restrict__ row2, const int* __restrict__ col2,
    int* __restrict__ cnt1, int* __restrict__ cnt2,
    int* __restrict__ csr1, int* __restrict__ csr2)
{
    const int b = blockIdx.x;
    const int tid = threadIdx.x;

    if (b < FILL_BLOCKS) {
        // ---- fill path ----
        const int* __restrict__ rowp;
        const int* __restrict__ colp;
        int* __restrict__ cnt;
        int* __restrict__ csr;
        int e0, e1, div;
        const int shard = b & 7;
        if (b < FILL1_BLOCKS) {
            int slice = b >> 3;
            e0 = slice * FILL1_SLICE; e1 = e0 + FILL1_SLICE;
            rowp = row1; colp = col1; cnt = cnt1; csr = csr1; div = 6250;
        } else {
            int slice = (b - FILL1_BLOCKS) >> 3;
            e0 = slice * FILL2_SLICE; e1 = e0 + FILL2_SLICE;
            rowp = row2; colp = col2; cnt = cnt2; csr = csr2; div = 1250;
        }
        const int lo = shard * div;          // wave-uniform shard column range
        // 8 edges per thread per pass. Loop 1: issue ALL claim atomics
        // (results buffered, no dependent use -> 8 outstanding per wave).
        // Loop 2: dependent scatter stores.
        for (int base = e0 + tid * 8; base < e1; base += 2048) {
            i32x4 c4a = __builtin_nontemporal_load((const i32x4*)(colp + base));
            i32x4 c4b = __builtin_nontemporal_load((const i32x4*)(colp + base + 4));
            i32x4 r4a = __builtin_nontemporal_load((const i32x4*)(rowp + base));
            i32x4 r4b = __builtin_nontemporal_load((const i32x4*)(rowp + base + 4));
            int pa[4], pb[4];
            #pragma unroll
            for (int k = 0; k < 4; ++k) {
                int c = c4a[k];
                pa[k] = ((u32)(c - lo) < (u32)div)
                        ? atomicAdd(cnt + (size_t)c * CSTR, 1) : CAP;
            }
            #pragma unroll
            for (int k = 0; k < 4; ++k) {
                int c = c4b[k];
                pb[k] = ((u32)(c - lo) < (u32)div)
                        ? atomicAdd(cnt + (size_t)c * CSTR, 1) : CAP;
            }
            #pragma unroll
            for (int k = 0; k < 4; ++k)
                if (pa[k] < CAP) csr[c4a[k] * CAP + pa[k]] = r4a[k];
            #pragma unroll
            for (int k = 0; k < 4; ++k)
                if (pb[k] < CAP) csr[c4b[k] * CAP + pb[k]] = r4b[k];
        }
    } else {
        // ---- prep path ----
        int i = (b - FILL_BLOCKS) * 256 + tid;
        if (i < NCONV8) {
            const fv4* x4 = (const fv4*)x;
            fv4 a = __builtin_nontemporal_load(x4 + i * 2);
            fv4 bb = __builtin_nontemporal_load(x4 + i * 2 + 1);
            uint4 o;
            o.x = pack2bf(a[0], a[1]); o.y = pack2bf(a[2], a[3]);
            o.z = pack2bf(bb[0], bb[1]); o.w = pack2bf(bb[2], bb[3]);
            ((uint4*)xb)[i] = o;
        } else if (i < NCONV8 + WTF_T) {
            int t = i - NCONV8;
            int layer = t >> 12;
            int rem = t & 4095;
            int kt = rem >> 9;
            int nt = (rem >> 6) & 7;
            int lane = rem & 63;
            int gn = nt * 16 + (lane & 15);      // global output column
            int k0 = kt * 32 + (lane >> 4) * 8;
            const float* Wl = layer ? Wl2 : Wl1;
            const float* Wr = layer ? Wr2 : Wr1;
            u16* WTf = layer ? WTf2 : WTf1;
            u32 o[4];
            #pragma unroll
            for (int p = 0; p < 4; ++p) {
                int ka = k0 + 2 * p, kb = ka + 1;
                float ea = (ka < 128) ? Wl[gn * 128 + ka] : Wr[gn * 128 + (ka - 128)];
                float eb = (kb < 128) ? Wl[gn * 128 + kb] : Wr[gn * 128 + (kb - 128)];
                o[p] = pack2bf(ea, eb);
            }
            ((uint4*)WTf)[(kt * 8 + nt) * 64 + lane] = make_uint4(o[0], o[1], o[2], o[3]);
        }
    }
}

// ---------------- fused SAGE layer kernel (bf16 gather + MFMA GEMM) ----------------
// Phase A: wave-per-row mean aggregation from fixed-stride buckets (deg<=48, one
//   chunk), 4 edges per uint4 gather, bf16-packed into LDS rows of 264 bf16.
// Phase B: [ROWS,256]bf16 @ B[256,128]bf16 via mfma_f32_16x16x32_bf16,
//   B pre-packed in fragment order; C -> LDS -> row L2-norm epilogue.

template <int ROWS, bool RELU, int MINB>
__global__ __launch_bounds__(256, MINB) void sage_kernel(
    const u16* __restrict__ xsrc_b, const u16* __restrict__ xdst_b,
    const int* __restrict__ cnt, const int* __restrict__ csrf,
    const u16* __restrict__ WTf, const float* __restrict__ bias,
    float* __restrict__ out_f, u16* __restrict__ out_b,
    int n_dst, int fp32lim)
{
    __shared__ float smem[ROWS * 132];   // bf16 [ROWS][264] == fp32 [ROWS][132]
    const int tid = threadIdx.x;
    const int i0 = blockIdx.x * ROWS;
    const int lane = tid & 63;
    const int w = tid >> 6;
    const int quarter = lane >> 4;  // 0..3
    const int l16 = lane & 15;
    const int half = lane >> 5;
    const int l32 = lane & 31;
    constexpr int RPW = ROWS / 4;

    const uint4* __restrict__ xs4 = (const uint4*)xsrc_b;
    const uint2* __restrict__ xd2 = (const uint2*)xdst_b;
    uint4* sA4 = (uint4*)smem;          // agg store: row r -> index r*33 + l16
    uint2* sA2 = (uint2*)smem;          // root store: row r -> index r*66 + 32 + l32

    // ---- Phase A ----
    for (int q = 0; q < RPW; ++q) {
        int r = w * RPW + q;
        int i = i0 + r;
        if (i < n_dst) {
            int deg = cnt[(size_t)i * CSTR];
            if (deg > CAP) deg = CAP;
            float acc[8] = {0.f, 0.f, 0.f, 0.f, 0.f, 0.f, 0.f, 0.f};
            if (deg > 0) {
                const int* bp = csrf + (size_t)i * CAP;
                int iv = bp[lane < deg ? lane : deg - 1];   // coalesced, clamped (valid rows)
                for (int g = 0; g < deg; g += 16) {
                    #pragma unroll
                    for (int j = 0; j < 4; ++j) {
                        if (g + 4 * j < deg) {              // wave-uniform guard
                            int rel = g + 4 * j + quarter;
                            int idx = __shfl(iv, rel & 63);
                            float m = (rel < deg) ? 1.f : 0.f;
                            uint4 u = xs4[(size_t)idx * 16 + l16];
                            acc[0] += m * bf_lo(u.x); acc[1] += m * bf_hi(u.x);
                            acc[2] += m * bf_lo(u.y); acc[3] += m * bf_hi(u.y);
                            acc[4] += m * bf_lo(u.z); acc[5] += m * bf_hi(u.z);
                            acc[6] += m * bf_lo(u.w); acc[7] += m * bf_hi(u.w);
                        }
                    }
                }
                #pragma unroll
                for (int k = 0; k < 8; ++k) {
                    acc[k] += __shfl_xor(acc[k], 16);
                    acc[k] += __shfl_xor(acc[k], 32);
                }
            }
            float s = (deg > 0) ? 1.f / (float)deg : 0.f;
            if (quarter == 0) {
                uint4 o;
                o.x = pack2bf(acc[0] * s, acc[1] * s);
                o.y = pack2bf(acc[2] * s, acc[3] * s);
                o.z = pack2bf(acc[4] * s, acc[5] * s);
                o.w = pack2bf(acc[6] * s, acc[7] * s);
                sA4[r * 33 + l16] = o;
            }
            if (half == 1) {
                sA2[r * 66 + 32 + l32] = xd2[(size_t)i * 32 + l32];
            }
        } else {
            if (quarter == 0) sA4[r * 33 + l16] = make_uint4(0, 0, 0, 0);
            if (half == 1)    sA2[r * 66 + 32 + l32] = make_uint2(0, 0);
        }
    }
    __syncthreads();

    // ---- Phase B: MFMA [ROWS,256] @ [256,128] ----
    constexpr int MT = ROWS / 16;       // 2 (layer1) or 1 (layer2)
    const int nt0 = w * 2;              // each wave: two N-tiles
    const s16x8* sAv = (const s16x8*)smem;      // A-frag: (mt*16 + l16)*33 + kt*4 + quarter
    const s16x8* Bv = (const s16x8*)WTf;        // B-frag: (kt*8 + nt)*64 + lane

    f32x4 C[MT][2];
    #pragma unroll
    for (int mt = 0; mt < MT; ++mt)
        #pragma unroll
        for (int ni = 0; ni < 2; ++ni)
            C[mt][ni] = (f32x4){0.f, 0.f, 0.f, 0.f};

    #pragma unroll
    for (int kt = 0; kt < 8; ++kt) {
        s16x8 a[MT];
        #pragma unroll
        for (int mt = 0; mt < MT; ++mt)
            a[mt] = sAv[(mt * 16 + l16) * 33 + kt * 4 + quarter];
        s16x8 b0 = Bv[(kt * 8 + nt0) * 64 + lane];
        s16x8 b1 = Bv[(kt * 8 + nt0 + 1) * 64 + lane];
        #pragma unroll
        for (int mt = 0; mt < MT; ++mt) {
            C[mt][0] = __builtin_amdgcn_mfma_f32_16x16x32_bf16(a[mt], b0, C[mt][0], 0, 0, 0);
            C[mt][1] = __builtin_amdgcn_mfma_f32_16x16x32_bf16(a[mt], b1, C[mt][1], 0, 0, 0);
        }
    }

    __syncthreads();   // done reading sA; reuse as sOut
    float* sOut = smem;                 // [ROWS][132]

    #pragma unroll
    for (int ni = 0; ni < 2; ++ni) {
        int col = (nt0 + ni) * 16 + l16;
        float bc = bias[col];
        #pragma unroll
        for (int mt = 0; mt < MT; ++mt) {
            #pragma unroll
            for (int r = 0; r < 4; ++r) {
                int row = mt * 16 + quarter * 4 + r;
                sOut[row * 132 + col] = C[mt][ni][r] + bc;
            }
        }
    }
    __syncthreads();

    // ---- epilogue: row L2-norm, ReLU, store ----
    constexpr int R = ROWS / 8;
    const int ty = tid >> 5;
    const int tx = tid & 31;
    #pragma unroll
    for (int r = 0; r < R; ++r) {
        int row = ty * R + r;
        float4 v = *(const float4*)(&sOut[row * 132 + tx * 4]);
        float s = v.x * v.x + v.y * v.y + v.z * v.z + v.w * v.w;
        #pragma unroll
        for (int off = 1; off < 32; off <<= 1) s += __shfl_xor(s, off);
        float scale = 1.f / fmaxf(sqrtf(s), 1e-12f);
        float v0 = v.x * scale, v1 = v.y * scale, v2 = v.z * scale, v3 = v.w * scale;
        if (RELU) {
            v0 = fmaxf(v0, 0.f); v1 = fmaxf(v1, 0.f);
            v2 = fmaxf(v2, 0.f); v3 = fmaxf(v3, 0.f);
        }
        int i = i0 + row;
        if (i < n_dst) {
            if (i < fp32lim)
                *(float4*)(out_f + (size_t)i * DD + tx * 4) = make_float4(v0, v1, v2, v3);
            if (out_b) {
                uint2 ob;
                ob.x = pack2bf(v0, v1);
                ob.y = pack2bf(v2, v3);
                *(uint2*)(out_b + (size_t)i * DD + tx * 4) = ob;
            }
        }
    }
}

// ---------------- launcher ----------------

extern "C" void kernel_launch(void* const* d_in, const int* in_sizes, int n_in,
                              void* d_out, int out_size, void* d_ws, size_t ws_size,
                              hipStream_t stream) {
    const float* x    = (const float*)d_in[0];
    const float* Wl1  = (const float*)d_in[1];
    const float* bl1  = (const float*)d_in[2];
    const float* Wr1  = (const float*)d_in[3];
    const float* Wl2  = (const float*)d_in[4];
    const float* bl2  = (const float*)d_in[5];
    const float* Wr2  = (const float*)d_in[6];
    const int* row1   = (const int*)d_in[7];
    const int* col1   = (const int*)d_in[8];
    const int* row2   = (const int*)d_in[9];
    const int* col2   = (const int*)d_in[10];
    float* out = (float*)d_out;

    // workspace carve (~79.5 MB -- same budget as the verified round-0/1 runs)
    char* p = (char*)d_ws;
    u16* xb    = (u16*)p;   p += (size_t)N_SRC * DD * sizeof(u16);    // 51.2 MB
    u16* hb    = (u16*)p;   p += (size_t)N_MID * DD * sizeof(u16);    // 12.8 MB
    u16* WTf1  = (u16*)p;   p += (size_t)256 * 128 * sizeof(u16);     // 64 KB
    u16* WTf2  = (u16*)p;   p += (size_t)256 * 128 * sizeof(u16);
    int* cnt1  = (int*)p;   p += (size_t)N_MID * CSTR * sizeof(int);  // 3.2 MB
    int* cnt2  = (int*)p;   p += (size_t)N_DST * CSTR * sizeof(int);  // 0.64 MB
    int* csr1  = (int*)p;   p += (size_t)N_MID * CAP * sizeof(int);   // 9.6 MB
    int* csr2  = (int*)p;   p += (size_t)N_DST * CAP * sizeof(int);   // 1.92 MB

    // 1) zero padded bucket counters (graph-capturable stream ops)
    (void)hipMemsetAsync(cnt1, 0, (size_t)N_MID * CSTR * sizeof(int), stream);
    (void)hipMemsetAsync(cnt2, 0, (size_t)N_DST * CSTR * sizeof(int), stream);

    // 2) fused: XCD-sharded CSR fill (blocks 0..1919, deterministic XCD map)
    //    + x->bf16 convert + weight fragment pack (blocks 1920..)
    prep_fill<<<PF_BLOCKS, 256, 0, stream>>>(
        x, xb, Wl1, Wr1, WTf1, Wl2, Wr2, WTf2,
        row1, col1, row2, col2, cnt1, cnt2, csr1, csr2);

    // 3) layer 1: gather/root from xb; write bf16 h
    sage_kernel<32, true, 6><<<(N_MID + 31) / 32, 256, 0, stream>>>(
        xb, xb, cnt1, csr1, WTf1, bl1, (float*)nullptr, hb, N_MID, 0);

    // 4) layer 2: gather/root from hb; write fp32 output
    sage_kernel<16, false, 6><<<(N_DST + 15) / 16, 256, 0, stream>>>(
        hb, hb, cnt2, csr2, WTf2, bl2, out, (u16*)nullptr, N_DST, N_DST);
}

// Round 7
// 273.349 us; speedup vs baseline: 1.0395x; 1.0395x over previous
//
#include <hip/hip_runtime.h>
#include <hip/hip_bf16.h>

#define DD 128
#define N_SRC 200000
#define N_MID 50000
#define N_DST 10000
#define E1 800000
#define E2 160000
#define CAP 48        // bucket capacity; deg ~ Poisson(16), P(deg>48) ~ 1e-11

typedef unsigned short u16;
typedef unsigned int u32;
typedef __attribute__((ext_vector_type(8))) short s16x8;   // 8 bf16 (4 VGPRs)
typedef __attribute__((ext_vector_type(4))) float f32x4;
typedef __attribute__((ext_vector_type(4))) int i32x4;
typedef __attribute__((ext_vector_type(4))) float fv4;

// ---------------- bf16 helpers ----------------

__device__ __forceinline__ float bf_lo(u32 u) {
    union { u32 u; float f; } v; v.u = u << 16; return v.f;
}
__device__ __forceinline__ float bf_hi(u32 u) {
    union { u32 u; float f; } v; v.u = u & 0xffff0000u; return v.f;
}
__device__ __forceinline__ u32 f2bf_bits(float f) {
    union { float f; u32 u; } v; v.f = f;
    return (v.u + 0x7fffu + ((v.u >> 16) & 1u)) >> 16;   // RTNE
}
__device__ __forceinline__ u32 pack2bf(float lo, float hi) {
    return f2bf_bits(lo) | (f2bf_bits(hi) << 16);
}

// ---------------- fused prep + fill1 kernel ----------------
// Rounds 1-6 ledger: fill time is invariant (~70us) under counter layout,
// claim ILP, and batch width -> memory-side RMW throughput bound (~1 atomic
// per L2 slice per ~22cy). Only FEWER atomics on the critical path helps:
// fill2 (160k atomics) is moved into the sage1 launch (hidden under gathers).
// prep_fill keeps fill1 (800k atomics) + x->bf16 + weight pack.

#define FILL1_SLICE  4000
#define FILL1_BLOCKS 1600          // 200 slices x 8 shards (all < 2048: XCD map holds)

#define NCONV8 (N_SRC * DD / 8)    // 400000
#define WTF_T 8192
#define PREP_T (NCONV8 + WTF_T)
#define PREP_BLOCKS ((PREP_T + 255) / 256)           // 1595
#define PF_BLOCKS (FILL1_BLOCKS + PREP_BLOCKS)

__global__ __launch_bounds__(256, 8) void prep_fill(
    const float* __restrict__ x, u16* __restrict__ xb,
    const float* __restrict__ Wl1, const float* __restrict__ Wr1,
    u16* __restrict__ WTf1,
    const float* __restrict__ Wl2, const float* __restrict__ Wr2,
    u16* __restrict__ WTf2,
    const int* __restrict__ row1, const int* __restrict__ col1,
    int* __restrict__ cnt1, int* __restrict__ csr1)
{
    const int b = blockIdx.x;
    const int tid = threadIdx.x;

    if (b < FILL1_BLOCKS) {
        // ---- fill1 path (round-5 verified pattern) ----
        int slice = b >> 3, shard = b & 7;
        int e0 = slice * FILL1_SLICE, e1 = e0 + FILL1_SLICE;
        const int lo = shard * 6250;
        for (int base = e0 + tid * 4; base < e1; base += 1024) {
            i32x4 c4 = __builtin_nontemporal_load((const i32x4*)(col1 + base));
            i32x4 r4 = __builtin_nontemporal_load((const i32x4*)(row1 + base));
            #pragma unroll
            for (int k = 0; k < 4; ++k) {
                int c = c4[k];
                if ((u32)(c - lo) < 6250u) {
                    int p = atomicAdd(cnt1 + c, 1);
                    if (p < CAP) csr1[c * CAP + p] = r4[k];
                }
            }
        }
    } else {
        // ---- prep path ----
        int i = (b - FILL1_BLOCKS) * 256 + tid;
        if (i < NCONV8) {
            const fv4* x4 = (const fv4*)x;
            fv4 a = __builtin_nontemporal_load(x4 + i * 2);
            fv4 bb = __builtin_nontemporal_load(x4 + i * 2 + 1);
            uint4 o;
            o.x = pack2bf(a[0], a[1]); o.y = pack2bf(a[2], a[3]);
            o.z = pack2bf(bb[0], bb[1]); o.w = pack2bf(bb[2], bb[3]);
            ((uint4*)xb)[i] = o;
        } else if (i < NCONV8 + WTF_T) {
            int t = i - NCONV8;
            int layer = t >> 12;
            int rem = t & 4095;
            int kt = rem >> 9;
            int nt = (rem >> 6) & 7;
            int lane = rem & 63;
            int gn = nt * 16 + (lane & 15);      // global output column
            int k0 = kt * 32 + (lane >> 4) * 8;
            const float* Wl = layer ? Wl2 : Wl1;
            const float* Wr = layer ? Wr2 : Wr1;
            u16* WTf = layer ? WTf2 : WTf1;
            u32 o[4];
            #pragma unroll
            for (int p = 0; p < 4; ++p) {
                int ka = k0 + 2 * p, kb = ka + 1;
                float ea = (ka < 128) ? Wl[gn * 128 + ka] : Wr[gn * 128 + (ka - 128)];
                float eb = (kb < 128) ? Wl[gn * 128 + kb] : Wr[gn * 128 + (kb - 128)];
                o[p] = pack2bf(ea, eb);
            }
            ((uint4*)WTf)[(kt * 8 + nt) * 64 + lane] = make_uint4(o[0], o[1], o[2], o[3]);
        }
    }
}

// ---------------- fused SAGE layer kernel (bf16 gather + MFMA GEMM) ----------------
// Blocks [0, nfill): layer-2 bucket fill (XCD-sharded; first-in-dispatch so
//   blockIdx&7 -> XCD mapping is deterministic). Hidden under sage1's gathers.
// Blocks [nfill, ...): SAGE layer.
// Phase A: wave-per-row mean aggregation. Degree loads hoisted (one
//   lane-parallel load per wave), bucket-list loads unclamped (csr zeroed by
//   memset -> masked lanes gather row 0 harmlessly) and prefetched one row
//   ahead: per-row chain drops from 3 serial round-trips to ~1.
// Phase B: [ROWS,256]bf16 @ B[256,128]bf16 via mfma_f32_16x16x32_bf16.

template <int ROWS, bool RELU, int MINB>
__global__ __launch_bounds__(256, MINB) void sage_kernel(
    const u16* __restrict__ xsrc_b, const u16* __restrict__ xdst_b,
    const int* __restrict__ cnt, const int* __restrict__ csrf,
    const u16* __restrict__ WTf, const float* __restrict__ bias,
    float* __restrict__ out_f, u16* __restrict__ out_b,
    int n_dst, int fp32lim,
    const int* __restrict__ frow, const int* __restrict__ fcol,
    int* __restrict__ fcnt, int* __restrict__ fcsr, int nfill)
{
    __shared__ float smem[ROWS * 132];   // bf16 [ROWS][264] == fp32 [ROWS][132]
    const int tid = threadIdx.x;

    if (blockIdx.x < nfill) {
        // ---- embedded layer-2 fill (40 slices x 4000 edges x 8 shards) ----
        int bb = blockIdx.x;
        int slice = bb >> 3, shard = bb & 7;
        int e0 = slice * 4000, e1 = e0 + 4000;
        const int lo = shard * 1250;
        for (int base = e0 + tid * 4; base < e1; base += 1024) {
            i32x4 c4 = __builtin_nontemporal_load((const i32x4*)(fcol + base));
            i32x4 r4 = __builtin_nontemporal_load((const i32x4*)(frow + base));
            #pragma unroll
            for (int k = 0; k < 4; ++k) {
                int c = c4[k];
                if ((u32)(c - lo) < 1250u) {
                    int p = atomicAdd(fcnt + c, 1);
                    if (p < CAP) fcsr[c * CAP + p] = r4[k];
                }
            }
        }
        return;
    }

    const int i0 = (blockIdx.x - nfill) * ROWS;
    const int lane = tid & 63;
    const int w = tid >> 6;
    const int quarter = lane >> 4;  // 0..3
    const int l16 = lane & 15;
    const int half = lane >> 5;
    const int l32 = lane & 31;
    constexpr int RPW = ROWS / 4;

    const uint4* __restrict__ xs4 = (const uint4*)xsrc_b;
    const uint2* __restrict__ xd2 = (const uint2*)xdst_b;
    uint4* sA4 = (uint4*)smem;          // agg store: row r -> index r*33 + l16
    uint2* sA2 = (uint2*)smem;          // root store: row r -> index r*66 + 32 + l32

    // ---- Phase A ----
    // hoisted degrees: lane q holds deg of row w*RPW+q
    int degv = 0;
    {
        int rr = i0 + w * RPW + lane;
        if (lane < RPW && rr < n_dst) degv = cnt[rr];
    }
    // prefetched bucket list for the first row (unclamped; csr zero-filled)
    int iv_next = 0;
    {
        int i = i0 + w * RPW;
        if (i < n_dst) iv_next = csrf[(size_t)i * CAP + lane];
    }

    for (int q = 0; q < RPW; ++q) {
        int r = w * RPW + q;
        int i = i0 + r;
        int deg = __shfl(degv, q);
        if (deg > CAP) deg = CAP;
        int iv = iv_next;
        if (q + 1 < RPW) {
            int i2 = i + 1;
            iv_next = (i2 < n_dst) ? csrf[(size_t)i2 * CAP + lane] : 0;
        }
        if (i < n_dst) {
            float acc[8] = {0.f, 0.f, 0.f, 0.f, 0.f, 0.f, 0.f, 0.f};
            if (deg > 0) {
                for (int g = 0; g < deg; g += 16) {
                    #pragma unroll
                    for (int j = 0; j < 4; ++j) {
                        if (g + 4 * j < deg) {              // wave-uniform guard
                            int rel = g + 4 * j + quarter;
                            int idx = __shfl(iv, rel & 63);
                            float m = (rel < deg) ? 1.f : 0.f;
                            uint4 u = xs4[(size_t)idx * 16 + l16];
                            acc[0] += m * bf_lo(u.x); acc[1] += m * bf_hi(u.x);
                            acc[2] += m * bf_lo(u.y); acc[3] += m * bf_hi(u.y);
                            acc[4] += m * bf_lo(u.z); acc[5] += m * bf_hi(u.z);
                            acc[6] += m * bf_lo(u.w); acc[7] += m * bf_hi(u.w);
                        }
                    }
                }
                #pragma unroll
                for (int k = 0; k < 8; ++k) {
                    acc[k] += __shfl_xor(acc[k], 16);
                    acc[k] += __shfl_xor(acc[k], 32);
                }
            }
            float s = (deg > 0) ? 1.f / (float)deg : 0.f;
            if (quarter == 0) {
                uint4 o;
                o.x = pack2bf(acc[0] * s, acc[1] * s);
                o.y = pack2bf(acc[2] * s, acc[3] * s);
                o.z = pack2bf(acc[4] * s, acc[5] * s);
                o.w = pack2bf(acc[6] * s, acc[7] * s);
                sA4[r * 33 + l16] = o;
            }
            if (half == 1) {
                sA2[r * 66 + 32 + l32] = xd2[(size_t)i * 32 + l32];
            }
        } else {
            if (quarter == 0) sA4[r * 33 + l16] = make_uint4(0, 0, 0, 0);
            if (half == 1)    sA2[r * 66 + 32 + l32] = make_uint2(0, 0);
        }
    }
    __syncthreads();

    // ---- Phase B: MFMA [ROWS,256] @ [256,128] ----
    constexpr int MT = ROWS / 16;       // 2 (layer1) or 1 (layer2)
    const int nt0 = w * 2;              // each wave: two N-tiles
    const s16x8* sAv = (const s16x8*)smem;      // A-frag: (mt*16 + l16)*33 + kt*4 + quarter
    const s16x8* Bv = (const s16x8*)WTf;        // B-frag: (kt*8 + nt)*64 + lane

    f32x4 C[MT][2];
    #pragma unroll
    for (int mt = 0; mt < MT; ++mt)
        #pragma unroll
        for (int ni = 0; ni < 2; ++ni)
            C[mt][ni] = (f32x4){0.f, 0.f, 0.f, 0.f};

    #pragma unroll
    for (int kt = 0; kt < 8; ++kt) {
        s16x8 a[MT];
        #pragma unroll
        for (int mt = 0; mt < MT; ++mt)
            a[mt] = sAv[(mt * 16 + l16) * 33 + kt * 4 + quarter];
        s16x8 b0 = Bv[(kt * 8 + nt0) * 64 + lane];
        s16x8 b1 = Bv[(kt * 8 + nt0 + 1) * 64 + lane];
        #pragma unroll
        for (int mt = 0; mt < MT; ++mt) {
            C[mt][0] = __builtin_amdgcn_mfma_f32_16x16x32_bf16(a[mt], b0, C[mt][0], 0, 0, 0);
            C[mt][1] = __builtin_amdgcn_mfma_f32_16x16x32_bf16(a[mt], b1, C[mt][1], 0, 0, 0);
        }
    }

    __syncthreads();   // done reading sA; reuse as sOut
    float* sOut = smem;                 // [ROWS][132]

    #pragma unroll
    for (int ni = 0; ni < 2; ++ni) {
        int col = (nt0 + ni) * 16 + l16;
        float bc = bias[col];
        #pragma unroll
        for (int mt = 0; mt < MT; ++mt) {
            #pragma unroll
            for (int r = 0; r < 4; ++r) {
                int row = mt * 16 + quarter * 4 + r;
                sOut[row * 132 + col] = C[mt][ni][r] + bc;
            }
        }
    }
    __syncthreads();

    // ---- epilogue: row L2-norm, ReLU, store ----
    constexpr int R = ROWS / 8;
    const int ty = tid >> 5;
    const int tx = tid & 31;
    #pragma unroll
    for (int r = 0; r < R; ++r) {
        int row = ty * R + r;
        float4 v = *(const float4*)(&sOut[row * 132 + tx * 4]);
        float s = v.x * v.x + v.y * v.y + v.z * v.z + v.w * v.w;
        #pragma unroll
        for (int off = 1; off < 32; off <<= 1) s += __shfl_xor(s, off);
        float scale = 1.f / fmaxf(sqrtf(s), 1e-12f);
        float v0 = v.x * scale, v1 = v.y * scale, v2 = v.z * scale, v3 = v.w * scale;
        if (RELU) {
            v0 = fmaxf(v0, 0.f); v1 = fmaxf(v1, 0.f);
            v2 = fmaxf(v2, 0.f); v3 = fmaxf(v3, 0.f);
        }
        int i = i0 + row;
        if (i < n_dst) {
            if (i < fp32lim)
                *(float4*)(out_f + (size_t)i * DD + tx * 4) = make_float4(v0, v1, v2, v3);
            if (out_b) {
                uint2 ob;
                ob.x = pack2bf(v0, v1);
                ob.y = pack2bf(v2, v3);
                *(uint2*)(out_b + (size_t)i * DD + tx * 4) = ob;
            }
        }
    }
}

// ---------------- launcher ----------------

#define NF2 320   // layer-2 fill blocks embedded in the sage1 launch

extern "C" void kernel_launch(void* const* d_in, const int* in_sizes, int n_in,
                              void* d_out, int out_size, void* d_ws, size_t ws_size,
                              hipStream_t stream) {
    const float* x    = (const float*)d_in[0];
    const float* Wl1  = (const float*)d_in[1];
    const float* bl1  = (const float*)d_in[2];
    const float* Wr1  = (const float*)d_in[3];
    const float* Wl2  = (const float*)d_in[4];
    const float* bl2  = (const float*)d_in[5];
    const float* Wr2  = (const float*)d_in[6];
    const int* row1   = (const int*)d_in[7];
    const int* col1   = (const int*)d_in[8];
    const int* row2   = (const int*)d_in[9];
    const int* col2   = (const int*)d_in[10];
    float* out = (float*)d_out;

    // workspace carve (~75.9 MB; cnt1..csr2 contiguous for a single memset)
    char* p = (char*)d_ws;
    u16* xb    = (u16*)p;   p += (size_t)N_SRC * DD * sizeof(u16);    // 51.2 MB
    u16* hb    = (u16*)p;   p += (size_t)N_MID * DD * sizeof(u16);    // 12.8 MB
    u16* WTf1  = (u16*)p;   p += (size_t)256 * 128 * sizeof(u16);     // 64 KB
    u16* WTf2  = (u16*)p;   p += (size_t)256 * 128 * sizeof(u16);
    char* zbase = p;
    int* cnt1  = (int*)p;   p += (size_t)N_MID * sizeof(int);         // 200 KB
    int* cnt2  = (int*)p;   p += (size_t)N_DST * sizeof(int);         // 40 KB
    int* csr1  = (int*)p;   p += (size_t)N_MID * CAP * sizeof(int);   // 9.6 MB
    int* csr2  = (int*)p;   p += (size_t)N_DST * CAP * sizeof(int);   // 1.92 MB
    size_t zlen = (size_t)(p - zbase);

    // 1) zero counters + buckets in ONE stream memset (buckets must be zeroed:
    //    Phase A reads them unclamped)
    (void)hipMemsetAsync(zbase, 0, zlen, stream);

    // 2) fused: XCD-sharded layer-1 CSR fill + x->bf16 + weight pack
    prep_fill<<<PF_BLOCKS, 256, 0, stream>>>(
        x, xb, Wl1, Wr1, WTf1, Wl2, Wr2, WTf2, row1, col1, cnt1, csr1);

    // 3) layer 1 sage + embedded layer-2 fill (blocks 0..NF2-1, deterministic
    //    XCD map since they dispatch first)
    sage_kernel<32, true, 6><<<NF2 + (N_MID + 31) / 32, 256, 0, stream>>>(
        xb, xb, cnt1, csr1, WTf1, bl1, (float*)nullptr, hb, N_MID, 0,
        row2, col2, cnt2, csr2, NF2);

    // 4) layer 2: gather/root from hb; write fp32 output
    sage_kernel<16, false, 6><<<(N_DST + 15) / 16, 256, 0, stream>>>(
        hb, hb, cnt2, csr2, WTf2, bl2, out, (u16*)nullptr, N_DST, N_DST,
        nullptr, nullptr, nullptr, nullptr, 0);
}

// Round 8
// 252.370 us; speedup vs baseline: 1.1259x; 1.0831x over previous
//
#include <hip/hip_runtime.h>
#include <hip/hip_bf16.h>

#define DD 128
#define N_SRC 200000
#define N_MID 50000
#define N_DST 10000
#define E1 800000
#define E2 160000
#define CAP 48        // fine bucket capacity; deg ~ Poisson(16), P(deg>48) ~ 1e-11

// ---- two-level countersort geometry ----
#define BK_W  200     // columns per coarse bucket
#define NB1   250     // coarse buckets layer 1 (250*200 = 50000)
#define NB2   50      // coarse buckets layer 2 (50*200 = 10000)
#define CCAP  3584    // coarse capacity; mean 3200, sigma ~57 -> +6.8 sigma
#define P1E   2048    // edges per pass-1 block (8 per thread)
#define NP1_1 ((E1 + P1E - 1) / P1E)   // 391
#define NP1_2 ((E2 + P1E - 1) / P1E)   // 79
#define P1_BLOCKS (NP1_1 + NP1_2)      // 470

typedef unsigned short u16;
typedef unsigned int u32;
typedef __attribute__((ext_vector_type(8))) short s16x8;   // 8 bf16 (4 VGPRs)
typedef __attribute__((ext_vector_type(4))) float f32x4;
typedef __attribute__((ext_vector_type(4))) float fv4;

// ---------------- bf16 helpers ----------------

__device__ __forceinline__ float bf_lo(u32 u) {
    union { u32 u; float f; } v; v.u = u << 16; return v.f;
}
__device__ __forceinline__ float bf_hi(u32 u) {
    union { u32 u; float f; } v; v.u = u & 0xffff0000u; return v.f;
}
__device__ __forceinline__ u32 f2bf_bits(float f) {
    union { float f; u32 u; } v; v.f = f;
    return (v.u + 0x7fffu + ((v.u >> 16) & 1u)) >> 16;   // RTNE
}
__device__ __forceinline__ u32 pack2bf(float lo, float hi) {
    return f2bf_bits(lo) | (f2bf_bits(hi) << 16);
}

// ---------------- kernel A: prep + coarse partition (pass 1) ----------------
// Rounds 1-7 ledger: fill time is LINEAR in global-atomic count (r7: 5/6 the
// atomics -> 61/70 the time); layout/ILP all null. So pass 1 replaces 960k
// per-edge atomics with per-(block,coarse-bucket) range claims: LDS-atomic
// local ranks, then ONE global atomicAdd per non-empty bucket per block
// (~102k total, 9.4x fewer), scatter into claimed contiguous chunks.
// Atomic wall ~7us hides under prep's ~28us streaming BW.

#define NCONV8 (N_SRC * DD / 8)    // 400000
#define WTF_T 8192
#define PREP_T (NCONV8 + WTF_T)
#define PREP_BLOCKS ((PREP_T + 255) / 256)           // 1595
#define PA_BLOCKS (P1_BLOCKS + PREP_BLOCKS)

__global__ __launch_bounds__(256, 8) void prep_part(
    const float* __restrict__ x, u16* __restrict__ xb,
    const float* __restrict__ Wl1, const float* __restrict__ Wr1,
    u16* __restrict__ WTf1,
    const float* __restrict__ Wl2, const float* __restrict__ Wr2,
    u16* __restrict__ WTf2,
    const int* __restrict__ row1, const int* __restrict__ col1,
    const int* __restrict__ row2, const int* __restrict__ col2,
    int* __restrict__ ccnt1, int* __restrict__ ccnt2,
    int2* __restrict__ cbuf1, int2* __restrict__ cbuf2)
{
    __shared__ int lcnt[256];
    __shared__ int gbase[256];
    const int b = blockIdx.x;
    const int tid = threadIdx.x;

    if (b < P1_BLOCKS) {
        // ---- pass-1 partition ----
        const int* __restrict__ colp;
        const int* __restrict__ rowp;
        int* __restrict__ ccnt;
        int2* __restrict__ cbuf;
        int e0, ne, nb;
        if (b < NP1_1) {
            colp = col1; rowp = row1; ccnt = ccnt1; cbuf = cbuf1;
            e0 = b * P1E; ne = E1 - e0; if (ne > P1E) ne = P1E; nb = NB1;
        } else {
            int bb = b - NP1_1;
            colp = col2; rowp = row2; ccnt = ccnt2; cbuf = cbuf2;
            e0 = bb * P1E; ne = E2 - e0; if (ne > P1E) ne = P1E; nb = NB2;
        }
        for (int t = tid; t < nb; t += 256) lcnt[t] = 0;
        __syncthreads();
        // scan 1: local rank per edge via LDS atomics (pack bk|rank, 16b each)
        int ep[8];
        #pragma unroll
        for (int j = 0; j < 8; ++j) {
            int e = tid + j * 256;
            ep[j] = -1;
            if (e < ne) {
                int c = colp[e0 + e];          // plain load: reread in scan 3 hits L2
                int bk = c / BK_W;             // compile-time magic-mul
                int rk = atomicAdd(&lcnt[bk], 1);
                ep[j] = (bk << 16) | rk;
            }
        }
        __syncthreads();
        // claim one contiguous global range per non-empty bucket
        for (int t = tid; t < nb; t += 256) {
            int c = lcnt[t];
            gbase[t] = c ? atomicAdd(&ccnt[t], c) : 0;
        }
        __syncthreads();
        // scan 3: chunk-contiguous scatter of (col,row) pairs
        #pragma unroll
        for (int j = 0; j < 8; ++j) {
            if (ep[j] >= 0) {
                int e = e0 + tid + j * 256;
                int bk = ep[j] >> 16;
                int pos = gbase[bk] + (ep[j] & 0xffff);
                if (pos < CCAP)
                    cbuf[(size_t)bk * CCAP + pos] = make_int2(colp[e], rowp[e]);
            }
        }
    } else {
        // ---- prep path ----
        int i = (b - P1_BLOCKS) * 256 + tid;
        if (i < NCONV8) {
            const fv4* x4 = (const fv4*)x;
            fv4 a = __builtin_nontemporal_load(x4 + i * 2);
            fv4 bb = __builtin_nontemporal_load(x4 + i * 2 + 1);
            uint4 o;
            o.x = pack2bf(a[0], a[1]); o.y = pack2bf(a[2], a[3]);
            o.z = pack2bf(bb[0], bb[1]); o.w = pack2bf(bb[2], bb[3]);
            ((uint4*)xb)[i] = o;
        } else if (i < NCONV8 + WTF_T) {
            int t = i - NCONV8;
            int layer = t >> 12;
            int rem = t & 4095;
            int kt = rem >> 9;
            int nt = (rem >> 6) & 7;
            int lane = rem & 63;
            int gn = nt * 16 + (lane & 15);      // global output column
            int k0 = kt * 32 + (lane >> 4) * 8;
            const float* Wl = layer ? Wl2 : Wl1;
            const float* Wr = layer ? Wr2 : Wr1;
            u16* WTf = layer ? WTf2 : WTf1;
            u32 o[4];
            #pragma unroll
            for (int p = 0; p < 4; ++p) {
                int ka = k0 + 2 * p, kb = ka + 1;
                float ea = (ka < 128) ? Wl[gn * 128 + ka] : Wr[gn * 128 + (ka - 128)];
                float eb = (kb < 128) ? Wl[gn * 128 + kb] : Wr[gn * 128 + (kb - 128)];
                o[p] = pack2bf(ea, eb);
            }
            ((uint4*)WTf)[(kt * 8 + nt) * 64 + lane] = make_uint4(o[0], o[1], o[2], o[3]);
        }
    }
}

// ---------------- kernel B: fine countersort (pass 2) ----------------
// One block per coarse bucket (exclusive owner of its 200 columns): coalesced
// pair loads, per-column rank via LDS histogram, ZERO global atomics, and the
// fine-CSR writes land in a private 38KB region (no cross-block interference).
// Writes true degree into cnt (same semantics as the old atomic counter).

__global__ __launch_bounds__(256, 8) void bucket_sort(
    const int2* __restrict__ cbuf1, const int2* __restrict__ cbuf2,
    const int* __restrict__ ccnt1, const int* __restrict__ ccnt2,
    int* __restrict__ cnt1, int* __restrict__ cnt2,
    int* __restrict__ csr1, int* __restrict__ csr2)
{
    const int b = blockIdx.x;
    const int tid = threadIdx.x;
    const int2* __restrict__ cbuf;
    const int* __restrict__ ccnt;
    int* __restrict__ cnt;
    int* __restrict__ csr;
    int bkt;
    if (b < NB1) { cbuf = cbuf1; ccnt = ccnt1; cnt = cnt1; csr = csr1; bkt = b; }
    else         { cbuf = cbuf2; ccnt = ccnt2; cnt = cnt2; csr = csr2; bkt = b - NB1; }
    const int col0 = bkt * BK_W;

    __shared__ int hist[BK_W];
    for (int t = tid; t < BK_W; t += 256) hist[t] = 0;
    __syncthreads();

    int n = ccnt[bkt]; if (n > CCAP) n = CCAP;
    const int2* bp = cbuf + (size_t)bkt * CCAP;
    for (int e = tid; e < n; e += 512) {         // 2-way ILP
        int2 cr0 = bp[e];
        int e1i = e + 256;
        bool h1 = e1i < n;
        int2 cr1 = h1 ? bp[e1i] : cr0;
        int r0 = atomicAdd(&hist[cr0.x - col0], 1);
        if (r0 < CAP) csr[cr0.x * CAP + r0] = cr0.y;
        if (h1) {
            int r1 = atomicAdd(&hist[cr1.x - col0], 1);
            if (r1 < CAP) csr[cr1.x * CAP + r1] = cr1.y;
        }
    }
    __syncthreads();
    for (int t = tid; t < BK_W; t += 256) cnt[col0 + t] = hist[t];
}

// ---------------- fused SAGE layer kernel (bf16 gather + MFMA GEMM) ----------------
// Phase A: wave-per-row mean aggregation; degrees hoisted, bucket lists
//   prefetched one row ahead, unclamped reads (csr zero-filled by memset).
// Phase B: [ROWS,256]bf16 @ B[256,128]bf16 via mfma_f32_16x16x32_bf16.

template <int ROWS, bool RELU, int MINB>
__global__ __launch_bounds__(256, MINB) void sage_kernel(
    const u16* __restrict__ xsrc_b, const u16* __restrict__ xdst_b,
    const int* __restrict__ cnt, const int* __restrict__ csrf,
    const u16* __restrict__ WTf, const float* __restrict__ bias,
    float* __restrict__ out_f, u16* __restrict__ out_b,
    int n_dst, int fp32lim)
{
    __shared__ float smem[ROWS * 132];   // bf16 [ROWS][264] == fp32 [ROWS][132]
    const int tid = threadIdx.x;
    const int i0 = blockIdx.x * ROWS;
    const int lane = tid & 63;
    const int w = tid >> 6;
    const int quarter = lane >> 4;  // 0..3
    const int l16 = lane & 15;
    const int half = lane >> 5;
    const int l32 = lane & 31;
    constexpr int RPW = ROWS / 4;

    const uint4* __restrict__ xs4 = (const uint4*)xsrc_b;
    const uint2* __restrict__ xd2 = (const uint2*)xdst_b;
    uint4* sA4 = (uint4*)smem;          // agg store: row r -> index r*33 + l16
    uint2* sA2 = (uint2*)smem;          // root store: row r -> index r*66 + 32 + l32

    // ---- Phase A ----
    int degv = 0;
    {
        int rr = i0 + w * RPW + lane;
        if (lane < RPW && rr < n_dst) degv = cnt[rr];
    }
    int iv_next = 0;
    {
        int i = i0 + w * RPW;
        if (i < n_dst) iv_next = csrf[(size_t)i * CAP + lane];
    }

    for (int q = 0; q < RPW; ++q) {
        int r = w * RPW + q;
        int i = i0 + r;
        int deg = __shfl(degv, q);
        if (deg > CAP) deg = CAP;
        int iv = iv_next;
        if (q + 1 < RPW) {
            int i2 = i + 1;
            iv_next = (i2 < n_dst) ? csrf[(size_t)i2 * CAP + lane] : 0;
        }
        if (i < n_dst) {
            float acc[8] = {0.f, 0.f, 0.f, 0.f, 0.f, 0.f, 0.f, 0.f};
            if (deg > 0) {
                for (int g = 0; g < deg; g += 16) {
                    #pragma unroll
                    for (int j = 0; j < 4; ++j) {
                        if (g + 4 * j < deg) {              // wave-uniform guard
                            int rel = g + 4 * j + quarter;
                            int idx = __shfl(iv, rel & 63);
                            float m = (rel < deg) ? 1.f : 0.f;
                            uint4 u = xs4[(size_t)idx * 16 + l16];
                            acc[0] += m * bf_lo(u.x); acc[1] += m * bf_hi(u.x);
                            acc[2] += m * bf_lo(u.y); acc[3] += m * bf_hi(u.y);
                            acc[4] += m * bf_lo(u.z); acc[5] += m * bf_hi(u.z);
                            acc[6] += m * bf_lo(u.w); acc[7] += m * bf_hi(u.w);
                        }
                    }
                }
                #pragma unroll
                for (int k = 0; k < 8; ++k) {
                    acc[k] += __shfl_xor(acc[k], 16);
                    acc[k] += __shfl_xor(acc[k], 32);
                }
            }
            float s = (deg > 0) ? 1.f / (float)deg : 0.f;
            if (quarter == 0) {
                uint4 o;
                o.x = pack2bf(acc[0] * s, acc[1] * s);
                o.y = pack2bf(acc[2] * s, acc[3] * s);
                o.z = pack2bf(acc[4] * s, acc[5] * s);
                o.w = pack2bf(acc[6] * s, acc[7] * s);
                sA4[r * 33 + l16] = o;
            }
            if (half == 1) {
                sA2[r * 66 + 32 + l32] = xd2[(size_t)i * 32 + l32];
            }
        } else {
            if (quarter == 0) sA4[r * 33 + l16] = make_uint4(0, 0, 0, 0);
            if (half == 1)    sA2[r * 66 + 32 + l32] = make_uint2(0, 0);
        }
    }
    __syncthreads();

    // ---- Phase B: MFMA [ROWS,256] @ [256,128] ----
    constexpr int MT = ROWS / 16;       // 2 (layer1) or 1 (layer2)
    const int nt0 = w * 2;              // each wave: two N-tiles
    const s16x8* sAv = (const s16x8*)smem;      // A-frag: (mt*16 + l16)*33 + kt*4 + quarter
    const s16x8* Bv = (const s16x8*)WTf;        // B-frag: (kt*8 + nt)*64 + lane

    f32x4 C[MT][2];
    #pragma unroll
    for (int mt = 0; mt < MT; ++mt)
        #pragma unroll
        for (int ni = 0; ni < 2; ++ni)
            C[mt][ni] = (f32x4){0.f, 0.f, 0.f, 0.f};

    #pragma unroll
    for (int kt = 0; kt < 8; ++kt) {
        s16x8 a[MT];
        #pragma unroll
        for (int mt = 0; mt < MT; ++mt)
            a[mt] = sAv[(mt * 16 + l16) * 33 + kt * 4 + quarter];
        s16x8 b0 = Bv[(kt * 8 + nt0) * 64 + lane];
        s16x8 b1 = Bv[(kt * 8 + nt0 + 1) * 64 + lane];
        #pragma unroll
        for (int mt = 0; mt < MT; ++mt) {
            C[mt][0] = __builtin_amdgcn_mfma_f32_16x16x32_bf16(a[mt], b0, C[mt][0], 0, 0, 0);
            C[mt][1] = __builtin_amdgcn_mfma_f32_16x16x32_bf16(a[mt], b1, C[mt][1], 0, 0, 0);
        }
    }

    __syncthreads();   // done reading sA; reuse as sOut
    float* sOut = smem;                 // [ROWS][132]

    #pragma unroll
    for (int ni = 0; ni < 2; ++ni) {
        int col = (nt0 + ni) * 16 + l16;
        float bc = bias[col];
        #pragma unroll
        for (int mt = 0; mt < MT; ++mt) {
            #pragma unroll
            for (int r = 0; r < 4; ++r) {
                int row = mt * 16 + quarter * 4 + r;
                sOut[row * 132 + col] = C[mt][ni][r] + bc;
            }
        }
    }
    __syncthreads();

    // ---- epilogue: row L2-norm, ReLU, store ----
    constexpr int R = ROWS / 8;
    const int ty = tid >> 5;
    const int tx = tid & 31;
    #pragma unroll
    for (int r = 0; r < R; ++r) {
        int row = ty * R + r;
        float4 v = *(const float4*)(&sOut[row * 132 + tx * 4]);
        float s = v.x * v.x + v.y * v.y + v.z * v.z + v.w * v.w;
        #pragma unroll
        for (int off = 1; off < 32; off <<= 1) s += __shfl_xor(s, off);
        float scale = 1.f / fmaxf(sqrtf(s), 1e-12f);
        float v0 = v.x * scale, v1 = v.y * scale, v2 = v.z * scale, v3 = v.w * scale;
        if (RELU) {
            v0 = fmaxf(v0, 0.f); v1 = fmaxf(v1, 0.f);
            v2 = fmaxf(v2, 0.f); v3 = fmaxf(v3, 0.f);
        }
        int i = i0 + row;
        if (i < n_dst) {
            if (i < fp32lim)
                *(float4*)(out_f + (size_t)i * DD + tx * 4) = make_float4(v0, v1, v2, v3);
            if (out_b) {
                uint2 ob;
                ob.x = pack2bf(v0, v1);
                ob.y = pack2bf(v2, v3);
                *(uint2*)(out_b + (size_t)i * DD + tx * 4) = ob;
            }
        }
    }
}

// ---------------- launcher ----------------

extern "C" void kernel_launch(void* const* d_in, const int* in_sizes, int n_in,
                              void* d_out, int out_size, void* d_ws, size_t ws_size,
                              hipStream_t stream) {
    const float* x    = (const float*)d_in[0];
    const float* Wl1  = (const float*)d_in[1];
    const float* bl1  = (const float*)d_in[2];
    const float* Wr1  = (const float*)d_in[3];
    const float* Wl2  = (const float*)d_in[4];
    const float* bl2  = (const float*)d_in[5];
    const float* Wr2  = (const float*)d_in[6];
    const int* row1   = (const int*)d_in[7];
    const int* col1   = (const int*)d_in[8];
    const int* row2   = (const int*)d_in[9];
    const int* col2   = (const int*)d_in[10];
    float* out = (float*)d_out;

    // workspace carve (~75.9 MB, same budget as the verified round-7 run).
    // cbuf (coarse partition, 8.6 MB) ALIASES hb: cbuf is dead after kernel B,
    // hb is first written by sage1 (strictly after) -- stream-ordered safe.
    char* p = (char*)d_ws;
    u16* xb    = (u16*)p;   p += (size_t)N_SRC * DD * sizeof(u16);    // 51.2 MB
    char* hbv  = p;         p += (size_t)N_MID * DD * sizeof(u16);    // 12.8 MB
    u16* hb    = (u16*)hbv;
    int2* cbuf1 = (int2*)hbv;                        // 250*3584*8 = 7.168 MB
    int2* cbuf2 = cbuf1 + (size_t)NB1 * CCAP;        // +50*3584*8 = 1.434 MB
    u16* WTf1  = (u16*)p;   p += (size_t)256 * 128 * sizeof(u16);     // 64 KB
    u16* WTf2  = (u16*)p;   p += (size_t)256 * 128 * sizeof(u16);
    char* zbase = p;
    int* ccnt1 = (int*)p;   p += 256 * sizeof(int);                   // 250 used
    int* ccnt2 = (int*)p;   p += 64 * sizeof(int);                    // 50 used
    int* cnt1  = (int*)p;   p += (size_t)N_MID * sizeof(int);         // 200 KB
    int* cnt2  = (int*)p;   p += (size_t)N_DST * sizeof(int);         // 40 KB
    int* csr1  = (int*)p;   p += (size_t)N_MID * CAP * sizeof(int);   // 9.6 MB
    int* csr2  = (int*)p;   p += (size_t)N_DST * CAP * sizeof(int);   // 1.92 MB
    p += 256;                                        // pad: Phase A reads 64 lanes
    size_t zlen = (size_t)(p - zbase);

    // 1) zero coarse counters + fine CSR (Phase A reads slots unclamped)
    (void)hipMemsetAsync(zbase, 0, zlen, stream);

    // 2) kernel A: prep (x->bf16, weight pack) + pass-1 coarse partition
    prep_part<<<PA_BLOCKS, 256, 0, stream>>>(
        x, xb, Wl1, Wr1, WTf1, Wl2, Wr2, WTf2,
        row1, col1, row2, col2, ccnt1, ccnt2, cbuf1, cbuf2);

    // 3) kernel B: fine countersort, both layers (zero global atomics)
    bucket_sort<<<NB1 + NB2, 256, 0, stream>>>(
        cbuf1, cbuf2, ccnt1, ccnt2, cnt1, cnt2, csr1, csr2);

    // 4) layer 1: gather/root from xb; write bf16 h
    sage_kernel<32, true, 6><<<(N_MID + 31) / 32, 256, 0, stream>>>(
        xb, xb, cnt1, csr1, WTf1, bl1, (float*)nullptr, hb, N_MID, 0);

    // 5) layer 2: gather/root from hb; write fp32 output
    sage_kernel<16, false, 6><<<(N_DST + 15) / 16, 256, 0, stream>>>(
        hb, hb, cnt2, csr2, WTf2, bl2, out, (u16*)nullptr, N_DST, N_DST);
}